// Round 9
// baseline (562.012 us; speedup 1.0000x reference)
//
#include <hip/hip_runtime.h>
#include <hip/hip_bf16.h>
#include <hip/hip_fp16.h>
#include <type_traits>

// f32 in / f32 out. Round-12: BARRIERLESS WAVE-AUTONOMOUS RESTRUCTURE.
// Evidence r0..r8: duration insensitive to occupancy (37% vs 67% -> same
// ~46us VALU-busy, worse duration w/ spills); the invariant is the
// block-barrier-per-32-edge-tile structure. This kernel removes it:
// - B-frag trick: mfma_16x16x32 B-layout = lane(quad,nlo) holds 16 contiguous
//   bytes of row nlo at k-offset quad*8 -> a wave gathers 16 edges' pair
//   products DIRECTLY into MFMA fragments (no LDS staging, no barrier).
// - W1 (f16, 64KB) + b1/w2 (f32, 2KB) live in LDS per block, filled once,
//   ONE barrier total. A-frags read back per 16-hidden group (swizzled
//   bits 4-5 -> 4-way conflict max; bit 6+ lives in the ds imm offset).
// - Each wave owns a PAIR of 16-edge tiles (T=2 for MFMA ILP): 16 groups x
//   {4 ds_read + 8 mfma + 8 mish/fc2}, then xor16/xor32 reduce + sigmoid +
//   store. 15625 pairs over 8192 waves (512 blocks x 16 waves, 2 blocks/CU).
// Keeps: fp16 z pre-pass (zcvt), swapped-operand MFMA, f32 mish.

#define N_NODES 100000
#define N_EDGES 500000
#define D_IN    128
#define D_HID   256
#define PAIRS   (N_EDGES / 32)       // 15625 exactly
#define GRID    512                  // 2 blocks/CU (LDS-capped)
#define TOTAL_WAVES (GRID * 16)

typedef _Float16 half8  __attribute__((ext_vector_type(8)));
typedef __fp16   fp16x2 __attribute__((ext_vector_type(2)));
typedef __bf16   bf16x8 __attribute__((ext_vector_type(8)));
typedef float    f32x4  __attribute__((ext_vector_type(4)));

__device__ __forceinline__ unsigned int pkh_u32(float a, float b) {
    fp16x2 r = __builtin_amdgcn_cvt_pkrtz(a, b);
    return __builtin_bit_cast(unsigned int, r);
}
__device__ __forceinline__ unsigned int pkbf_u32(float a, float b) {
    union { __hip_bfloat162 v; unsigned int u; } c;
    c.v = __float22bfloat162_rn(make_float2(a, b));
    return c.u;
}

// mish(x) = x * N/(N+2), N = E*(E+2), E = e^min(x,20)
__device__ __forceinline__ float mishf(float x) {
    float E   = __expf(fminf(x, 20.0f));
    float num = E * (E + 2.0f);
    return x * num * __builtin_amdgcn_rcpf(num + 2.0f);
}
__device__ __forceinline__ float sigf(float x) {
    return __builtin_amdgcn_rcpf(1.0f + __expf(-x));
}

// ---- pre-pass: z f32 -> fp16 (RNE), fully coalesced, BW-bound ----
__global__ __launch_bounds__(256)
void zcvt_kernel(const float* __restrict__ z, _Float16* __restrict__ zh) {
    const size_t i = (size_t)blockIdx.x * 256 + threadIdx.x;   // chunk id
    const float4 f0 = *reinterpret_cast<const float4*>(z + i * 8);
    const float4 f1 = *reinterpret_cast<const float4*>(z + i * 8 + 4);
    union { half8 h; uint4 u; } o;
    o.h[0] = (_Float16)f0.x; o.h[1] = (_Float16)f0.y;
    o.h[2] = (_Float16)f0.z; o.h[3] = (_Float16)f0.w;
    o.h[4] = (_Float16)f1.x; o.h[5] = (_Float16)f1.y;
    o.h[6] = (_Float16)f1.z; o.h[7] = (_Float16)f1.w;
    *reinterpret_cast<uint4*>(zh + i * 8) = o.u;
}

template <bool USE_H>
__global__ __launch_bounds__(1024, 4)
void edge_mlp_kernel(const float*    __restrict__ z,
                     const _Float16* __restrict__ zh,
                     const int*      __restrict__ edge,
                     const float*    __restrict__ W1,
                     const float*    __restrict__ b1,
                     const float*    __restrict__ W2,
                     const float*    __restrict__ b2,
                     float*          __restrict__ out) {
    using frag_t = std::conditional_t<USE_H, half8, bf16x8>;

    // smem: [0,1024) b1 f32 | [1024,2048) w2 f32 | [2048, 2048+65536) W1 f16
    __shared__ __align__(16) char smem[2048 + D_HID * D_IN * 2];

    const int t = threadIdx.x;

    // ---- fill b1 / w2 (f32) ----
    if (t < 256) {
        ((float*)smem)[t]          = b1[t];
        ((float*)(smem + 1024))[t] = W2[t];
    }
    // ---- fill W1 as f16, swizzled: 4096 chunks of 16B, 4 per thread ----
    #pragma unroll
    for (int i = 0; i < 4; ++i) {
        const int c    = t + i * 1024;
        const int h    = c >> 4;          // hidden row 0..255
        const int slot = c & 15;          // 16B slot in row
        const float* src = W1 + h * D_IN + slot * 8;
        const float4 f0 = *reinterpret_cast<const float4*>(src);
        const float4 f1 = *reinterpret_cast<const float4*>(src + 4);
        union { uint4 u; } o;
        if constexpr (USE_H) {
            o.u = make_uint4(pkh_u32(f0.x, f0.y), pkh_u32(f0.z, f0.w),
                             pkh_u32(f1.x, f1.y), pkh_u32(f1.z, f1.w));
        } else {
            o.u = make_uint4(pkbf_u32(f0.x, f0.y), pkbf_u32(f0.z, f0.w),
                             pkbf_u32(f1.x, f1.y), pkbf_u32(f1.z, f1.w));
        }
        char* dst = smem + 2048 + h * 256 + ((slot * 16) ^ ((h & 3) << 4));
        *reinterpret_cast<uint4*>(dst) = o.u;
    }
    __syncthreads();   // the ONLY barrier

    const int wave = t >> 6;
    const int lane = t & 63;
    const int quad = lane >> 4;
    const int nlo  = lane & 15;
    const int gw   = (blockIdx.x << 4) + wave;   // 0..8191

    // A-frag base: row nlo of each group, swizzle bits 4-5 in the register
    const char*  ldsA  = smem + 2048 + nlo * 256 + ((quad * 16) ^ ((nlo & 3) << 4));
    const float* ldsB1 = (const float*)(smem + quad * 16);          // + g*16 floats
    const float* ldsW2 = (const float*)(smem + 1024 + quad * 16);
    const float  b2f   = b2[0];

    for (int pi = gw; pi < PAIRS; pi += TOTAL_WAVES) {
        const int e0 = pi * 32 + nlo;
        const int u0 = edge[e0],              v0 = edge[N_EDGES + e0];
        const int u1 = edge[e0 + 16],         v1 = edge[N_EDGES + e0 + 16];

        // ---- gather pair-products directly into B-fragments ----
        frag_t bf0[4], bf1[4];
        if constexpr (USE_H) {
            const char* zb = reinterpret_cast<const char*>(zh) + quad * 16;
            const char* pu0 = zb + ((size_t)u0 << 8);
            const char* pv0 = zb + ((size_t)v0 << 8);
            const char* pu1 = zb + ((size_t)u1 << 8);
            const char* pv1 = zb + ((size_t)v1 << 8);
            #pragma unroll
            for (int ks = 0; ks < 4; ++ks) {
                half8 a = *reinterpret_cast<const half8*>(pu0 + ks * 64);
                half8 c = *reinterpret_cast<const half8*>(pv0 + ks * 64);
                bf0[ks] = a * c;                      // 4x v_pk_mul_f16
            }
            #pragma unroll
            for (int ks = 0; ks < 4; ++ks) {
                half8 a = *reinterpret_cast<const half8*>(pu1 + ks * 64);
                half8 c = *reinterpret_cast<const half8*>(pv1 + ks * 64);
                bf1[ks] = a * c;
            }
        } else {
            const char* zb = reinterpret_cast<const char*>(z) + quad * 32;
            const char* pu0 = zb + ((size_t)u0 << 9);
            const char* pv0 = zb + ((size_t)v0 << 9);
            const char* pu1 = zb + ((size_t)u1 << 9);
            const char* pv1 = zb + ((size_t)v1 << 9);
            #pragma unroll
            for (int ks = 0; ks < 4; ++ks) {
                float4 a0 = *reinterpret_cast<const float4*>(pu0 + ks * 128);
                float4 a1 = *reinterpret_cast<const float4*>(pu0 + ks * 128 + 16);
                float4 c0 = *reinterpret_cast<const float4*>(pv0 + ks * 128);
                float4 c1 = *reinterpret_cast<const float4*>(pv0 + ks * 128 + 16);
                union { uint4 u; bf16x8 v; } o;
                o.u = make_uint4(pkbf_u32(a0.x*c0.x, a0.y*c0.y),
                                 pkbf_u32(a0.z*c0.z, a0.w*c0.w),
                                 pkbf_u32(a1.x*c1.x, a1.y*c1.y),
                                 pkbf_u32(a1.z*c1.z, a1.w*c1.w));
                bf0[ks] = o.v;
            }
            #pragma unroll
            for (int ks = 0; ks < 4; ++ks) {
                float4 a0 = *reinterpret_cast<const float4*>(pu1 + ks * 128);
                float4 a1 = *reinterpret_cast<const float4*>(pu1 + ks * 128 + 16);
                float4 c0 = *reinterpret_cast<const float4*>(pv1 + ks * 128);
                float4 c1 = *reinterpret_cast<const float4*>(pv1 + ks * 128 + 16);
                union { uint4 u; bf16x8 v; } o;
                o.u = make_uint4(pkbf_u32(a0.x*c0.x, a0.y*c0.y),
                                 pkbf_u32(a0.z*c0.z, a0.w*c0.w),
                                 pkbf_u32(a1.x*c1.x, a1.y*c1.y),
                                 pkbf_u32(a1.z*c1.z, a1.w*c1.w));
                bf1[ks] = o.v;
            }
        }

        // ---- 16 hidden-groups: MFMA + fused mish/fc2 epilogue ----
        float l0 = 0.0f, l1 = 0.0f;
        #pragma unroll
        for (int g = 0; g < 16; ++g) {
            f32x4 acc0 = (f32x4){0.f, 0.f, 0.f, 0.f};
            f32x4 acc1 = (f32x4){0.f, 0.f, 0.f, 0.f};
            #pragma unroll
            for (int ks = 0; ks < 4; ++ks) {
                frag_t wf = *reinterpret_cast<const frag_t*>(
                                ldsA + g * 4096 + ks * 64);
                if constexpr (USE_H) {
                    acc0 = __builtin_amdgcn_mfma_f32_16x16x32_f16(wf, bf0[ks], acc0, 0, 0, 0);
                    acc1 = __builtin_amdgcn_mfma_f32_16x16x32_f16(wf, bf1[ks], acc1, 0, 0, 0);
                } else {
                    acc0 = __builtin_amdgcn_mfma_f32_16x16x32_bf16(wf, bf0[ks], acc0, 0, 0, 0);
                    acc1 = __builtin_amdgcn_mfma_f32_16x16x32_bf16(wf, bf1[ks], acc1, 0, 0, 0);
                }
            }
            const float4 b1v = *reinterpret_cast<const float4*>(ldsB1 + g * 16);
            const float4 w2v = *reinterpret_cast<const float4*>(ldsW2 + g * 16);
            const float bb[4] = {b1v.x, b1v.y, b1v.z, b1v.w};
            const float ww[4] = {w2v.x, w2v.y, w2v.z, w2v.w};
            #pragma unroll
            for (int i = 0; i < 4; ++i) {
                l0 = fmaf(mishf(acc0[i] + bb[i]), ww[i], l0);
                l1 = fmaf(mishf(acc1[i] + bb[i]), ww[i], l1);
            }
        }

        // ---- cross-quad reduce (hidden split over quads) + sigmoid + store ----
        l0 += __shfl_xor(l0, 16);  l0 += __shfl_xor(l0, 32);
        l1 += __shfl_xor(l1, 16);  l1 += __shfl_xor(l1, 32);
        if (quad == 0) {
            out[pi * 32 + nlo]      = sigf(l0 + b2f);
            out[pi * 32 + 16 + nlo] = sigf(l1 + b2f);
        }
    }
}

extern "C" void kernel_launch(void* const* d_in, const int* in_sizes, int n_in,
                              void* d_out, int out_size, void* d_ws, size_t ws_size,
                              hipStream_t stream) {
    const float* z    = (const float*)d_in[0];
    const int*   edge = (const int*)d_in[1];
    const float* W1   = (const float*)d_in[2];
    const float* b1   = (const float*)d_in[3];
    const float* W2   = (const float*)d_in[4];
    const float* b2   = (const float*)d_in[5];
    float* out = (float*)d_out;

    const size_t zh_bytes = (size_t)N_NODES * D_IN * sizeof(_Float16);  // 25.6 MB
    if (d_ws != nullptr && ws_size >= zh_bytes) {
        _Float16* zh = (_Float16*)d_ws;
        zcvt_kernel<<<dim3(N_NODES * D_IN / 8 / 256), dim3(256), 0, stream>>>(z, zh);
        edge_mlp_kernel<true><<<dim3(GRID), dim3(1024), 0, stream>>>(
            z, zh, edge, W1, b1, W2, b2, out);
    } else {
        edge_mlp_kernel<false><<<dim3(GRID), dim3(1024), 0, stream>>>(
            z, nullptr, edge, W1, b1, W2, b2, out);
    }
}

// Round 10
// 163.098 us; speedup vs baseline: 3.4459x; 3.4459x over previous
//
#include <hip/hip_runtime.h>
#include <hip/hip_bf16.h>
#include <hip/hip_fp16.h>
#include <type_traits>

// f32 in / f32 out. Round-13: BARRIERLESS, SPILL-FIXED. r9's 477us was pure
// scratch spill (WRITE_SIZE 653MB): full unroll of the g=16 loop hoisted 16
// groups of LDS loads into ~128+ live regs under a capped file. The gather-
// direct-to-B-fragment structure itself is hardware-verified correct (absmax
// unchanged). Fixes: (1) #pragma unroll 2 on the group loop (bounded live
// set); (2) 512-thread blocks + __launch_bounds__(512,4) (the r7-proven
// no-spill point, natural ~90 < 128 cap); (3) W1 LDS row stride 288B in
// place of the XOR swizzle -> lane bank phase (nlo*8+quad*4)%32 spreads 64
// lanes over all 8 16B slices (b128 conflict-free; r9's swizzle was 16-way).
// Keeps: T=2 tiles/wave (one W1 ds_read feeds both MFMAs), fp16 z pre-pass,
// swapped MFMA, f32 mish, ONE barrier total (after W1 fill).

#define N_NODES 100000
#define N_EDGES 500000
#define D_IN    128
#define D_HID   256
#define PAIRS   (N_EDGES / 32)       // 15625 exactly
#define GRID    512                  // 2 blocks/CU (LDS-capped)
#define NWAVES  8
#define TOTAL_WAVES (GRID * NWAVES)  // 4096
#define LDS_ROW 288                  // 256B row + 32B pad -> 8-slice bank phase

typedef _Float16 half8  __attribute__((ext_vector_type(8)));
typedef __fp16   fp16x2 __attribute__((ext_vector_type(2)));
typedef __bf16   bf16x8 __attribute__((ext_vector_type(8)));
typedef float    f32x4  __attribute__((ext_vector_type(4)));

__device__ __forceinline__ unsigned int pkh_u32(float a, float b) {
    fp16x2 r = __builtin_amdgcn_cvt_pkrtz(a, b);
    return __builtin_bit_cast(unsigned int, r);
}
__device__ __forceinline__ unsigned int pkbf_u32(float a, float b) {
    union { __hip_bfloat162 v; unsigned int u; } c;
    c.v = __float22bfloat162_rn(make_float2(a, b));
    return c.u;
}

// mish(x) = x * N/(N+2), N = E*(E+2), E = e^min(x,20)
__device__ __forceinline__ float mishf(float x) {
    float E   = __expf(fminf(x, 20.0f));
    float num = E * (E + 2.0f);
    return x * num * __builtin_amdgcn_rcpf(num + 2.0f);
}
__device__ __forceinline__ float sigf(float x) {
    return __builtin_amdgcn_rcpf(1.0f + __expf(-x));
}

// ---- pre-pass: z f32 -> fp16 (RNE), fully coalesced, BW-bound ----
__global__ __launch_bounds__(256)
void zcvt_kernel(const float* __restrict__ z, _Float16* __restrict__ zh) {
    const size_t i = (size_t)blockIdx.x * 256 + threadIdx.x;   // chunk id
    const float4 f0 = *reinterpret_cast<const float4*>(z + i * 8);
    const float4 f1 = *reinterpret_cast<const float4*>(z + i * 8 + 4);
    union { half8 h; uint4 u; } o;
    o.h[0] = (_Float16)f0.x; o.h[1] = (_Float16)f0.y;
    o.h[2] = (_Float16)f0.z; o.h[3] = (_Float16)f0.w;
    o.h[4] = (_Float16)f1.x; o.h[5] = (_Float16)f1.y;
    o.h[6] = (_Float16)f1.z; o.h[7] = (_Float16)f1.w;
    *reinterpret_cast<uint4*>(zh + i * 8) = o.u;
}

template <bool USE_H>
__global__ __launch_bounds__(512, 4)
void edge_mlp_kernel(const float*    __restrict__ z,
                     const _Float16* __restrict__ zh,
                     const int*      __restrict__ edge,
                     const float*    __restrict__ W1,
                     const float*    __restrict__ b1,
                     const float*    __restrict__ W2,
                     const float*    __restrict__ b2,
                     float*          __restrict__ out) {
    using frag_t = std::conditional_t<USE_H, half8, bf16x8>;

    // smem: [0,1024) b1 f32 | [1024,2048) w2 f32 | [2048,...) W1 f16 rows@288B
    __shared__ __align__(16) char smem[2048 + D_HID * LDS_ROW];   // 74 KB

    const int t = threadIdx.x;

    // ---- fill b1 / w2 (f32) ----
    if (t < 256) {
        ((float*)smem)[t]          = b1[t];
        ((float*)(smem + 1024))[t] = W2[t];
    }
    // ---- fill W1 as f16: 4096 chunks of 16B, 8 per thread, stride-288 rows ----
    #pragma unroll
    for (int i = 0; i < 8; ++i) {
        const int c    = t + i * 512;
        const int h    = c >> 4;          // hidden row 0..255
        const int slot = c & 15;          // 16B slot in row
        const float* src = W1 + h * D_IN + slot * 8;
        const float4 f0 = *reinterpret_cast<const float4*>(src);
        const float4 f1 = *reinterpret_cast<const float4*>(src + 4);
        uint4 o;
        if constexpr (USE_H) {
            o = make_uint4(pkh_u32(f0.x, f0.y), pkh_u32(f0.z, f0.w),
                           pkh_u32(f1.x, f1.y), pkh_u32(f1.z, f1.w));
        } else {
            o = make_uint4(pkbf_u32(f0.x, f0.y), pkbf_u32(f0.z, f0.w),
                           pkbf_u32(f1.x, f1.y), pkbf_u32(f1.z, f1.w));
        }
        *reinterpret_cast<uint4*>(smem + 2048 + h * LDS_ROW + slot * 16) = o;
    }
    __syncthreads();   // the ONLY barrier

    const int wave = t >> 6;
    const int lane = t & 63;
    const int quad = lane >> 4;
    const int nlo  = lane & 15;
    const int gw   = (blockIdx.x << 3) + wave;   // 0..4095

    // A-frag base: row nlo, byte offset quad*16; group g adds g*16*LDS_ROW,
    // k-slice adds ks*64 (immediate-friendly).
    const char*  ldsA  = smem + 2048 + nlo * LDS_ROW + quad * 16;
    const float* ldsB1 = (const float*)(smem + quad * 16);
    const float* ldsW2 = (const float*)(smem + 1024 + quad * 16);
    const float  b2f   = b2[0];

    for (int pi = gw; pi < PAIRS; pi += TOTAL_WAVES) {
        const int e0 = pi * 32 + nlo;
        const int u0 = edge[e0],      v0 = edge[N_EDGES + e0];
        const int u1 = edge[e0 + 16], v1 = edge[N_EDGES + e0 + 16];

        // ---- gather pair-products directly into B-fragments ----
        frag_t bf0[4], bf1[4];
        if constexpr (USE_H) {
            const char* zb = reinterpret_cast<const char*>(zh) + quad * 16;
            const char* pu0 = zb + ((size_t)u0 << 8);
            const char* pv0 = zb + ((size_t)v0 << 8);
            const char* pu1 = zb + ((size_t)u1 << 8);
            const char* pv1 = zb + ((size_t)v1 << 8);
            #pragma unroll
            for (int ks = 0; ks < 4; ++ks) {
                half8 a = *reinterpret_cast<const half8*>(pu0 + ks * 64);
                half8 c = *reinterpret_cast<const half8*>(pv0 + ks * 64);
                bf0[ks] = a * c;                      // 4x v_pk_mul_f16
            }
            #pragma unroll
            for (int ks = 0; ks < 4; ++ks) {
                half8 a = *reinterpret_cast<const half8*>(pu1 + ks * 64);
                half8 c = *reinterpret_cast<const half8*>(pv1 + ks * 64);
                bf1[ks] = a * c;
            }
        } else {
            const char* zb = reinterpret_cast<const char*>(z) + quad * 32;
            const char* pu0 = zb + ((size_t)u0 << 9);
            const char* pv0 = zb + ((size_t)v0 << 9);
            const char* pu1 = zb + ((size_t)u1 << 9);
            const char* pv1 = zb + ((size_t)v1 << 9);
            #pragma unroll
            for (int ks = 0; ks < 4; ++ks) {
                float4 a0 = *reinterpret_cast<const float4*>(pu0 + ks * 128);
                float4 a1 = *reinterpret_cast<const float4*>(pu0 + ks * 128 + 16);
                float4 c0 = *reinterpret_cast<const float4*>(pv0 + ks * 128);
                float4 c1 = *reinterpret_cast<const float4*>(pv0 + ks * 128 + 16);
                union { uint4 u; bf16x8 v; } o;
                o.u = make_uint4(pkbf_u32(a0.x*c0.x, a0.y*c0.y),
                                 pkbf_u32(a0.z*c0.z, a0.w*c0.w),
                                 pkbf_u32(a1.x*c1.x, a1.y*c1.y),
                                 pkbf_u32(a1.z*c1.z, a1.w*c1.w));
                bf0[ks] = o.v;
            }
            #pragma unroll
            for (int ks = 0; ks < 4; ++ks) {
                float4 a0 = *reinterpret_cast<const float4*>(pu1 + ks * 128);
                float4 a1 = *reinterpret_cast<const float4*>(pu1 + ks * 128 + 16);
                float4 c0 = *reinterpret_cast<const float4*>(pv1 + ks * 128);
                float4 c1 = *reinterpret_cast<const float4*>(pv1 + ks * 128 + 16);
                union { uint4 u; bf16x8 v; } o;
                o.u = make_uint4(pkbf_u32(a0.x*c0.x, a0.y*c0.y),
                                 pkbf_u32(a0.z*c0.z, a0.w*c0.w),
                                 pkbf_u32(a1.x*c1.x, a1.y*c1.y),
                                 pkbf_u32(a1.z*c1.z, a1.w*c1.w));
                bf1[ks] = o.v;
            }
        }

        // ---- 16 hidden-groups: MFMA + fused mish/fc2 epilogue ----
        // unroll 2: bounded live set (r9 lesson — full unroll spilled 653MB)
        float l0 = 0.0f, l1 = 0.0f;
        #pragma unroll 2
        for (int g = 0; g < 16; ++g) {
            f32x4 acc0 = (f32x4){0.f, 0.f, 0.f, 0.f};
            f32x4 acc1 = (f32x4){0.f, 0.f, 0.f, 0.f};
            const char* lA = ldsA + g * (16 * LDS_ROW);
            #pragma unroll
            for (int ks = 0; ks < 4; ++ks) {
                frag_t wf = *reinterpret_cast<const frag_t*>(lA + ks * 64);
                if constexpr (USE_H) {
                    acc0 = __builtin_amdgcn_mfma_f32_16x16x32_f16(wf, bf0[ks], acc0, 0, 0, 0);
                    acc1 = __builtin_amdgcn_mfma_f32_16x16x32_f16(wf, bf1[ks], acc1, 0, 0, 0);
                } else {
                    acc0 = __builtin_amdgcn_mfma_f32_16x16x32_bf16(wf, bf0[ks], acc0, 0, 0, 0);
                    acc1 = __builtin_amdgcn_mfma_f32_16x16x32_bf16(wf, bf1[ks], acc1, 0, 0, 0);
                }
            }
            const float4 b1v = *reinterpret_cast<const float4*>(ldsB1 + g * 16);
            const float4 w2v = *reinterpret_cast<const float4*>(ldsW2 + g * 16);
            const float bb[4] = {b1v.x, b1v.y, b1v.z, b1v.w};
            const float ww[4] = {w2v.x, w2v.y, w2v.z, w2v.w};
            #pragma unroll
            for (int i = 0; i < 4; ++i) {
                l0 = fmaf(mishf(acc0[i] + bb[i]), ww[i], l0);
                l1 = fmaf(mishf(acc1[i] + bb[i]), ww[i], l1);
            }
        }

        // ---- cross-quad reduce (hidden split over quads) + sigmoid + store ----
        l0 += __shfl_xor(l0, 16);  l0 += __shfl_xor(l0, 32);
        l1 += __shfl_xor(l1, 16);  l1 += __shfl_xor(l1, 32);
        if (quad == 0) {
            out[pi * 32 + nlo]      = sigf(l0 + b2f);
            out[pi * 32 + 16 + nlo] = sigf(l1 + b2f);
        }
    }
}

extern "C" void kernel_launch(void* const* d_in, const int* in_sizes, int n_in,
                              void* d_out, int out_size, void* d_ws, size_t ws_size,
                              hipStream_t stream) {
    const float* z    = (const float*)d_in[0];
    const int*   edge = (const int*)d_in[1];
    const float* W1   = (const float*)d_in[2];
    const float* b1   = (const float*)d_in[3];
    const float* W2   = (const float*)d_in[4];
    const float* b2   = (const float*)d_in[5];
    float* out = (float*)d_out;

    const size_t zh_bytes = (size_t)N_NODES * D_IN * sizeof(_Float16);  // 25.6 MB
    if (d_ws != nullptr && ws_size >= zh_bytes) {
        _Float16* zh = (_Float16*)d_ws;
        zcvt_kernel<<<dim3(N_NODES * D_IN / 8 / 256), dim3(256), 0, stream>>>(z, zh);
        edge_mlp_kernel<true><<<dim3(GRID), dim3(512), 0, stream>>>(
            z, zh, edge, W1, b1, W2, b2, out);
    } else {
        edge_mlp_kernel<false><<<dim3(GRID), dim3(512), 0, stream>>>(
            z, nullptr, edge, W1, b1, W2, b2, out);
    }
}